// Round 11
// baseline (174.918 us; speedup 1.0000x reference)
//
#include <hip/hip_runtime.h>

#define A_N 8192
#define OBS_D 520
#define EMB 64
#define HID 128
#define NACT 6
#define SPLIT 16

typedef short bf16x8 __attribute__((ext_vector_type(8)));
typedef _Float16 half8 __attribute__((ext_vector_type(8)));
typedef float f32x4 __attribute__((ext_vector_type(4)));
typedef unsigned short u16;
typedef unsigned int u32;

#define MFMA_BF(a,b,c) __builtin_amdgcn_mfma_f32_16x16x32_bf16(a,b,c,0,0,0)
#define MFMA_FH(a,b,c) __builtin_amdgcn_mfma_f32_16x16x32_f16(a,b,c,0,0,0)

__device__ inline u32 fbits(float f){ union{float f; u32 u;}v; v.f=f; return v.u; }
__device__ inline float fval(u32 u){ union{u32 u; float f;}v; v.u=u; return v.f; }
__device__ inline u16 f2bf(float f){ u32 u=fbits(f); u += 0x7fffu + ((u>>16)&1u); return (u16)(u>>16); }
// pack trunc-bf16(pe) low, trunc-bf16(po) high
__device__ inline u32 pk_bf(float pe, float po){
  return __builtin_amdgcn_perm(fbits(po), fbits(pe), 0x07060302u);
}
__device__ inline float sigmoidf_fast(float x){
  x = fminf(fmaxf(x, -30.f), 30.f);
  return 1.f / (1.f + __expf(-x));
}
__device__ inline float tanhf_fast(float x){
  x = fminf(fmaxf(x, -15.f), 15.f);
  float e = __expf(-2.f*x);
  return (1.f - e) / (1.f + e);
}

// exp2 constant: (1/sqrt(64)) * log2(e)
#define EXP2C 0.18033688011112042f

// ---------------------------------------------------------------------------
// kPrep2: fused weight-prep + belief projection. 166 blocks x 256. (R8-proven)
// ---------------------------------------------------------------------------
__global__ __launch_bounds__(256) void kPrep2(
    const float* __restrict__ Wg, const float* __restrict__ Wir,
    const float* __restrict__ Wiz, const float* __restrict__ Win,
    const float* __restrict__ Whr, const float* __restrict__ Whz,
    const float* __restrict__ Whn, const float* __restrict__ W1,
    const float* __restrict__ W2, const float* __restrict__ Wb,
    const float* __restrict__ beliefs, const float* __restrict__ bb,
    _Float16* __restrict__ WT, _Float16* __restrict__ W1T,
    _Float16* __restrict__ W2T, u16* __restrict__ bp, u16* __restrict__ bpT)
{
  __shared__ float tile[64][65];
  __shared__ u16 WbL[64][136];
  const int t = threadIdx.x, b = blockIdx.x;

  if (b < 38) {
    const float* src; int k0, c0, srcStride, kValid;
    if (b < 28) {
      const int mi = b >> 2, tl = b & 3;
      src = mi==0?Wg: mi==1?Wir: mi==2?Wiz: mi==3?Win: mi==4?Whr: mi==5?Whz: Whn;
      k0 = (tl >> 1) * 64; c0 = (tl & 1) * 64; srcStride = 128; kValid = 128;
    } else if (b < 37) {
      src = W1; k0 = (b - 28) * 64; c0 = 0; srcStride = 64; kValid = OBS_D;
    } else {
      src = W2; k0 = 0; c0 = 0; srcStride = 64; kValid = 64;
    }
    #pragma unroll
    for (int i = 0; i < 16; i++) {
      const int idx = i * 256 + t;
      const int rr = idx >> 6, cc = idx & 63;   // rr = k-local, cc = c-local
      tile[rr][cc] = (k0 + rr < kValid) ? src[(size_t)(k0 + rr) * srcStride + c0 + cc] : 0.f;
    }
    __syncthreads();
    if (b < 28) {
      const int mi = b >> 2;
      _Float16* dst = WT + (size_t)mi * 16384;
      #pragma unroll
      for (int i = 0; i < 16; i++) {
        const int idx = i * 256 + t;
        const int rr = idx >> 6, cc = idx & 63;  // rr = c-local, cc = k-local
        dst[(size_t)(c0 + rr) * 128 + k0 + cc] = (_Float16)tile[cc][rr];
      }
    } else if (b < 37) {
      #pragma unroll
      for (int i = 0; i < 16; i++) {
        const int idx = i * 256 + t;
        const int rr = idx >> 6, cc = idx & 63;
        if (k0 + cc < 544)
          W1T[(size_t)rr * 544 + k0 + cc] = (_Float16)tile[cc][rr];
      }
    } else {
      #pragma unroll
      for (int i = 0; i < 16; i++) {
        const int idx = i * 256 + t;
        const int rr = idx >> 6, cc = idx & 63;
        W2T[(size_t)rr * 64 + cc] = (_Float16)tile[cc][rr];
      }
    }
  } else {
    // ---------------- belief projection (self-contained) ----------------
    const int lane = t & 63, wid = t >> 6;
    const int m = lane & 15, quad = lane >> 4;
    const int r0 = (b - 38) * 64 + wid * 16;

    // Wb (128x64 f32) -> WbL[c][k] bf16, coalesced float4 reads
    #pragma unroll
    for (int i = 0; i < 8; i++) {
      const int i4 = i * 256 + t;               // 2048 float4s
      float4 w4 = ((const float4*)Wb)[i4];
      const int k = i4 >> 4, c = (i4 & 15) * 4;
      WbL[c+0][k] = f2bf(w4.x); WbL[c+1][k] = f2bf(w4.y);
      WbL[c+2][k] = f2bf(w4.z); WbL[c+3][k] = f2bf(w4.w);
    }
    __syncthreads();

    f32x4 acc[4];
    #pragma unroll
    for (int ct = 0; ct < 4; ct++) acc[ct] = (f32x4){0.f,0.f,0.f,0.f};
    #pragma unroll
    for (int s = 0; s < 4; s++) {
      const int k0 = s*32;
      const float* ap = beliefs + (size_t)(r0+m)*HID + k0 + quad*8;
      float4 a0 = *(const float4*)ap;
      float4 a1 = *(const float4*)(ap + 4);
      union { u16 e[8]; bf16x8 v; } av;
      av.e[0]=f2bf(a0.x); av.e[1]=f2bf(a0.y); av.e[2]=f2bf(a0.z); av.e[3]=f2bf(a0.w);
      av.e[4]=f2bf(a1.x); av.e[5]=f2bf(a1.y); av.e[6]=f2bf(a1.z); av.e[7]=f2bf(a1.w);
      #pragma unroll
      for (int ct = 0; ct < 4; ct++) {
        bf16x8 bw = *(const bf16x8*)&WbL[ct*16+m][k0 + quad*8];
        acc[ct] = MFMA_BF(av.v, bw, acc[ct]);
      }
    }
    #pragma unroll
    for (int ct = 0; ct < 4; ct++) {
      const int col = ct*16 + m;
      const float bbv = bb[col];
      u16 e[4];
      #pragma unroll
      for (int r = 0; r < 4; r++) e[r] = f2bf(acc[ct][r] + bbv);
      #pragma unroll
      for (int r = 0; r < 4; r++)
        bp[(size_t)(r0 + quad*4 + r)*EMB + col] = e[r];
      uint2 pkv;
      pkv.x = (u32)e[0] | ((u32)e[1] << 16);
      pkv.y = (u32)e[2] | ((u32)e[3] << 16);
      *(uint2*)(bpT + (size_t)col*A_N + r0 + quad*4) = pkv;
    }
  }
}

// ---------------------------------------------------------------------------
// kM: blocks 0..127 = obs-MLP; blocks 128..639 = flash attention.
// R11: K/V^T fragments hoisted from LDS into registers ONCE per tile (shared
// across both compute halves and all Q-frags). Cuts per-wave-tile LDS read
// traffic 72KB -> 40KB (K was read 2x, V 4x). Staging/barrier structure is
// the R10-proven double-buffered one-barrier-per-tile scheme.
// ---------------------------------------------------------------------------
__global__ __launch_bounds__(256) void kM(
    const u16* __restrict__ bp, const u16* __restrict__ bpT,
    u16* __restrict__ ctxp, float* __restrict__ sums,
    const float* __restrict__ obs, const _Float16* __restrict__ W1T,
    const float* __restrict__ b1, const _Float16* __restrict__ W2T,
    const float* __restrict__ b2, _Float16* __restrict__ h2f)
{
  __shared__ __align__(16) u16 KT[2][64*72];    // K tile,  18432 B
  __shared__ __align__(16) u16 VTl[2][64*72];   // V^T tile, 18432 B
  __shared__ __align__(16) u16 P2[4][2][16*72]; // per-wave P (2 frags), 18432 B
  const int tid = threadIdx.x;
  const int lane = tid & 63;
  const int wid  = tid >> 6;
  const int m = lane & 15, quad = lane >> 4;

  if (blockIdx.x >= 128) {
    // ------------------------- attention -------------------------
    const int ab = blockIdx.x - 128;          // 0..511
    const int split = ab >> 5;                // whole block shares one split
    const int qb = ab & 31;
    const int q0w = qb * 256 + wid * 64;      // wave's 64 q-rows
    const int kbeg = split * (A_N / SPLIT);

    bf16x8 qa[4][2];
    #pragma unroll
    for (int f = 0; f < 4; f++) {
      const u16* qr = bp + (size_t)(q0w + f*16 + m)*EMB + quad*8;
      qa[f][0] = *(const bf16x8*)(qr);
      qa[f][1] = *(const bf16x8*)(qr + 32);
    }
    f32x4 oacc[4][4];   // [f][dtt]
    #pragma unroll
    for (int f = 0; f < 4; f++)
      #pragma unroll
      for (int d = 0; d < 4; d++) oacc[f][d] = (f32x4){0.f,0.f,0.f,0.f};
    float rowsum[4] = {0.f, 0.f, 0.f, 0.f};

    uint4 kreg[2], vreg[2];
    const int srow0 = tid >> 3, seg = tid & 7;        // iter0 row, 16B segment
    const int srow1 = (256 + tid) >> 3;               // iter1 row

    // preload tile 0 -> buffer 0
    kreg[0] = *(const uint4*)(bp + (size_t)(kbeg + srow0)*EMB + seg*8);
    kreg[1] = *(const uint4*)(bp + (size_t)(kbeg + srow1)*EMB + seg*8);
    vreg[0] = *(const uint4*)(bpT + (size_t)srow0*A_N + kbeg + seg*8);
    vreg[1] = *(const uint4*)(bpT + (size_t)srow1*A_N + kbeg + seg*8);
    *(uint4*)&KT[0][srow0*72 + seg*8] = kreg[0];
    *(uint4*)&KT[0][srow1*72 + seg*8] = kreg[1];
    *(uint4*)&VTl[0][srow0*72 + seg*8] = vreg[0];
    *(uint4*)&VTl[0][srow1*72 + seg*8] = vreg[1];
    __syncthreads();

    for (int tt = 0; tt < 8; tt++) {
      const int k0 = kbeg + tt*64;
      const int cur = tt & 1;
      if (tt < 7) {   // issue next tile's loads now; consumed after compute
        const int kn = k0 + 64;
        kreg[0] = *(const uint4*)(bp + (size_t)(kn + srow0)*EMB + seg*8);
        kreg[1] = *(const uint4*)(bp + (size_t)(kn + srow1)*EMB + seg*8);
        vreg[0] = *(const uint4*)(bpT + (size_t)srow0*A_N + kn + seg*8);
        vreg[1] = *(const uint4*)(bpT + (size_t)srow1*A_N + kn + seg*8);
      }
      // hoist K and V^T fragments into registers ONCE per tile
      bf16x8 kbr[4][2], vbr[4][2];
      #pragma unroll
      for (int jt = 0; jt < 4; jt++) {
        kbr[jt][0] = *(const bf16x8*)&KT[cur][(jt*16+m)*72 + quad*8];
        kbr[jt][1] = *(const bf16x8*)&KT[cur][(jt*16+m)*72 + 32 + quad*8];
        vbr[jt][0] = *(const bf16x8*)&VTl[cur][(jt*16+m)*72 + quad*8];
        vbr[jt][1] = *(const bf16x8*)&VTl[cur][(jt*16+m)*72 + 32 + quad*8];
      }
      // compute in 2 halves of Q-frags (halves share the wave's P buffer pair)
      #pragma unroll
      for (int h = 0; h < 2; h++) {
        #pragma unroll
        for (int jt = 0; jt < 4; jt++) {
          #pragma unroll
          for (int fi = 0; fi < 2; fi++) {
            const int f = h*2 + fi;
            f32x4 s = (f32x4){0.f,0.f,0.f,0.f};
            s = MFMA_BF(kbr[jt][0], qa[f][0], s);
            s = MFMA_BF(kbr[jt][1], qa[f][1], s);
            float p0 = __builtin_amdgcn_exp2f(s[0]*EXP2C);
            float p1 = __builtin_amdgcn_exp2f(s[1]*EXP2C);
            float p2 = __builtin_amdgcn_exp2f(s[2]*EXP2C);
            float p3 = __builtin_amdgcn_exp2f(s[3]*EXP2C);
            if ((k0 + jt*16) == (q0w + f*16)) {   // wave-uniform diag tile
              const int jl = quad*4;
              if (jl + 0 == m) p0 = 0.f;
              if (jl + 1 == m) p1 = 0.f;
              if (jl + 2 == m) p2 = 0.f;
              if (jl + 3 == m) p3 = 0.f;
            }
            rowsum[f] += (p0 + p1) + (p2 + p3);
            uint2 pkv; pkv.x = pk_bf(p0, p1); pkv.y = pk_bf(p2, p3);
            *(uint2*)&P2[wid][fi][m*72 + jt*16 + quad*4] = pkv;
          }
        }
        // wave-local ds_write -> ds_read ordering (no block barrier)
        asm volatile("s_waitcnt lgkmcnt(0)" ::: "memory");
        #pragma unroll
        for (int fi = 0; fi < 2; fi++) {
          const int f = h*2 + fi;
          const bf16x8 pa0 = *(const bf16x8*)&P2[wid][fi][m*72 + quad*8];
          const bf16x8 pa1 = *(const bf16x8*)&P2[wid][fi][m*72 + 32 + quad*8];
          #pragma unroll
          for (int dtt = 0; dtt < 4; dtt++) {
            oacc[f][dtt] = MFMA_BF(pa0, vbr[dtt][0], oacc[f][dtt]);
            oacc[f][dtt] = MFMA_BF(pa1, vbr[dtt][1], oacc[f][dtt]);
          }
        }
      }
      if (tt < 7) {   // write next tile into idle buffer; single barrier
        const int nxt = cur ^ 1;
        *(uint4*)&KT[nxt][srow0*72 + seg*8] = kreg[0];
        *(uint4*)&KT[nxt][srow1*72 + seg*8] = kreg[1];
        *(uint4*)&VTl[nxt][srow0*72 + seg*8] = vreg[0];
        *(uint4*)&VTl[nxt][srow1*72 + seg*8] = vreg[1];
        __syncthreads();
      }
    }

    // rowsum for query q=m (per frag): reduce across the 4 quads
    #pragma unroll
    for (int f = 0; f < 4; f++) {
      float v = rowsum[f];
      v += __shfl_xor(v, 16, 64);
      v += __shfl_xor(v, 32, 64);
      if (lane < 16)
        sums[(size_t)split*A_N + q0w + f*16 + lane] = v;
    }
    // oacc[f][dtt][r] = ctx[q = q0w+f*16+quad*4+r][d = dtt*16+m]
    #pragma unroll
    for (int f = 0; f < 4; f++) {
      const size_t base = ((size_t)split*A_N + q0w + f*16) * EMB;
      #pragma unroll
      for (int dtt = 0; dtt < 4; dtt++)
        #pragma unroll
        for (int r = 0; r < 4; r++)
          ctxp[base + (size_t)(quad*4+r)*EMB + dtt*16 + m] = f2bf(oacc[f][dtt][r]);
    }
  } else {
    // ------------------------- obs-MLP -------------------------
    const int r0 = blockIdx.x * 64 + wid * 16;
    f32x4 oa[4];
    #pragma unroll
    for (int ct = 0; ct < 4; ct++) oa[ct] = (f32x4){0.f,0.f,0.f,0.f};

    for (int s = 0; s < 17; s++) {
      const int k0 = s * 32;
      union { _Float16 e[8]; half8 v; } af;
      if (s < 16) {
        const float* ap = obs + (size_t)(r0+m)*OBS_D + k0 + quad*8;
        float4 a0 = *(const float4*)ap;
        float4 a1 = *(const float4*)(ap + 4);
        af.e[0]=(_Float16)a0.x; af.e[1]=(_Float16)a0.y; af.e[2]=(_Float16)a0.z; af.e[3]=(_Float16)a0.w;
        af.e[4]=(_Float16)a1.x; af.e[5]=(_Float16)a1.y; af.e[6]=(_Float16)a1.z; af.e[7]=(_Float16)a1.w;
      } else {
        #pragma unroll
        for (int j = 0; j < 8; j++) af.e[j] = (_Float16)0.f;
        if (quad == 0) {
          const float* ap = obs + (size_t)(r0+m)*OBS_D + 512;
          float4 a0 = *(const float4*)ap;
          float4 a1 = *(const float4*)(ap + 4);
          af.e[0]=(_Float16)a0.x; af.e[1]=(_Float16)a0.y; af.e[2]=(_Float16)a0.z; af.e[3]=(_Float16)a0.w;
          af.e[4]=(_Float16)a1.x; af.e[5]=(_Float16)a1.y; af.e[6]=(_Float16)a1.z; af.e[7]=(_Float16)a1.w;
        }
      }
      #pragma unroll
      for (int ct = 0; ct < 4; ct++) {
        half8 bw = *(const half8*)(W1T + (size_t)(ct*16+m)*544 + k0 + quad*8);
        oa[ct] = MFMA_FH(af.v, bw, oa[ct]);
      }
    }
    _Float16* H1 = (_Float16*)&P2[wid][0][0];
    #pragma unroll
    for (int ct = 0; ct < 4; ct++) {
      const float b1v = b1[ct*16 + m];
      #pragma unroll
      for (int r = 0; r < 4; r++) {
        float v = fmaxf(oa[ct][r] + b1v, 0.f);
        H1[(quad*4+r)*72 + ct*16 + m] = (_Float16)v;
      }
    }
    __syncthreads();   // MLP blocks uniform; orders H1 write -> read
    f32x4 ob[4];
    #pragma unroll
    for (int ct = 0; ct < 4; ct++) ob[ct] = (f32x4){0.f,0.f,0.f,0.f};
    #pragma unroll
    for (int s2 = 0; s2 < 2; s2++) {
      half8 ah = *(const half8*)(H1 + m*72 + s2*32 + quad*8);
      #pragma unroll
      for (int ct = 0; ct < 4; ct++) {
        half8 bw = *(const half8*)(W2T + (size_t)(ct*16+m)*64 + s2*32 + quad*8);
        ob[ct] = MFMA_FH(ah, bw, ob[ct]);
      }
    }
    #pragma unroll
    for (int ct = 0; ct < 4; ct++) {
      const float b2v = b2[ct*16 + m];
      #pragma unroll
      for (int r = 0; r < 4; r++) {
        float v = fmaxf(ob[ct][r] + b2v, 0.f);
        h2f[(size_t)(r0 + quad*4 + r)*EMB + ct*16 + m] = (_Float16)v;
      }
    }
  }
}

// ---------------------------------------------------------------------------
// k3: split-reduce + GRU + logits. 32 rows/block, 256 blocks, 8 waves (512t).
// R11: 8 waves/block (wave = 1 col-tile x 2 row-tiles) doubles waves/CU at
// identical total weight VMEM; per-wave accumulators halve (lower VGPR).
// ---------------------------------------------------------------------------
__global__ __launch_bounds__(512) void k3_gru(
    const float* __restrict__ beliefs, const _Float16* __restrict__ h2f,
    const u16* __restrict__ ctxp, const float* __restrict__ sums,
    const _Float16* __restrict__ WT,
    const float* __restrict__ bg, const float* __restrict__ bhr,
    const float* __restrict__ bhz, const float* __restrict__ bhn,
    const float* __restrict__ Wout, const float* __restrict__ bout,
    float* __restrict__ out)
{
  __shared__ __align__(16) _Float16 xf[32][136];   // x = [h2|ctx]; then new_beliefs
  __shared__ __align__(16) _Float16 belf[32][136];
  __shared__ __align__(16) _Float16 gruf[32][136]; // gru_in; tail: Wout f32 stage
  __shared__ float invs[32];
  const int t = threadIdx.x;
  const int lane = t & 63, wid = t >> 6;           // wid 0..7 = col-tile
  const int m = lane & 15, quad = lane >> 4;
  const int r0 = blockIdx.x * 32;

  // Phase 0a: stage beliefs (f16) into LDS — 512 threads, one slot each
  {
    const int row = t >> 4, seg = t & 15;
    const float* bpR = beliefs + (size_t)(r0+row)*HID + seg*8;
    float4 a0 = *(const float4*)bpR;
    float4 a1 = *(const float4*)(bpR + 4);
    union { _Float16 e[8]; half8 v; } hb;
    hb.e[0]=(_Float16)a0.x; hb.e[1]=(_Float16)a0.y; hb.e[2]=(_Float16)a0.z; hb.e[3]=(_Float16)a0.w;
    hb.e[4]=(_Float16)a1.x; hb.e[5]=(_Float16)a1.y; hb.e[6]=(_Float16)a1.z; hb.e[7]=(_Float16)a1.w;
    *(half8*)&belf[row][seg*8] = hb.v;
  }
  // Phase 0b: h2 into xf; ctx split-reduce in registers (first 256 threads)
  if (t < 256) {
    const int crow = t >> 3, cg = t & 7;
    half8 hv = *(const half8*)(h2f + (size_t)(r0+crow)*EMB + cg*8);
    *(half8*)&xf[crow][cg*8] = hv;
    float ca[8];
    #pragma unroll
    for (int d = 0; d < 8; d++) ca[d] = 0.f;
    #pragma unroll
    for (int sp = 0; sp < SPLIT; sp++) {
      uint4 u = *(const uint4*)(ctxp + ((size_t)sp*A_N + r0 + crow)*EMB + cg*8);
      ca[0] += fval(u.x << 16); ca[1] += fval(u.x & 0xffff0000u);
      ca[2] += fval(u.y << 16); ca[3] += fval(u.y & 0xffff0000u);
      ca[4] += fval(u.z << 16); ca[5] += fval(u.z & 0xffff0000u);
      ca[6] += fval(u.w << 16); ca[7] += fval(u.w & 0xffff0000u);
    }
    float ss = 0.f;
    #pragma unroll
    for (int sp = 0; sp < SPLIT; sp++) ss += sums[(size_t)sp*A_N + r0 + crow];
    const float iv = 1.f / ss;
    union { _Float16 e[8]; half8 v; } hc;
    #pragma unroll
    for (int d = 0; d < 8; d++) hc.e[d] = (_Float16)(ca[d] * iv);
    *(half8*)&xf[crow][64 + cg*8] = hc.v;
  }
  __syncthreads();

  // Phase 1: gru_in = x @ Wg + bg  (wave owns col-tile wid x 2 row-tiles)
  f32x4 g[2];   // [rt]
  g[0] = (f32x4){0.f,0.f,0.f,0.f}; g[1] = (f32x4){0.f,0.f,0.f,0.f};
  #pragma unroll
  for (int s = 0; s < 4; s++) {
    half8 bw = *(const half8*)(WT + (size_t)(wid*16+m)*128 + s*32 + quad*8);
    #pragma unroll
    for (int rt = 0; rt < 2; rt++) {
      half8 ax = *(const half8*)&xf[rt*16 + m][s*32 + quad*8];
      g[rt] = MFMA_FH(ax, bw, g[rt]);
    }
  }
  {
    const int col = wid*16 + m;
    const float bgv = bg[col];
    #pragma unroll
    for (int rt = 0; rt < 2; rt++)
      #pragma unroll
      for (int r = 0; r < 4; r++)
        gruf[rt*16 + quad*4 + r][col] = (_Float16)(g[rt][r] + bgv);
  }
  __syncthreads();

  // Phase 2: gates
  f32x4 RV[2], ZV[2];
  #pragma unroll
  for (int gidx = 0; gidx < 3; gidx++) {
    const _Float16* WiTg = WT + (size_t)(1+gidx)*16384;
    const _Float16* WhTg = WT + (size_t)(4+gidx)*16384;
    f32x4 gi[2], gh[2];
    gi[0]=(f32x4){0.f,0.f,0.f,0.f}; gi[1]=(f32x4){0.f,0.f,0.f,0.f};
    gh[0]=(f32x4){0.f,0.f,0.f,0.f}; gh[1]=(f32x4){0.f,0.f,0.f,0.f};
    #pragma unroll
    for (int s = 0; s < 4; s++) {
      half8 bi = *(const half8*)(WiTg + (size_t)(wid*16+m)*128 + s*32 + quad*8);
      half8 bh = *(const half8*)(WhTg + (size_t)(wid*16+m)*128 + s*32 + quad*8);
      #pragma unroll
      for (int rt = 0; rt < 2; rt++) {
        half8 ag = *(const half8*)&gruf[rt*16 + m][s*32 + quad*8];
        half8 ab = *(const half8*)&belf[rt*16 + m][s*32 + quad*8];
        gi[rt] = MFMA_FH(ag, bi, gi[rt]);
        gh[rt] = MFMA_FH(ab, bh, gh[rt]);
      }
    }
    const int col = wid*16 + m;
    if (gidx == 0) {
      const float bv = bhr[col];
      #pragma unroll
      for (int rt = 0; rt < 2; rt++)
        #pragma unroll
        for (int r = 0; r < 4; r++)
          RV[rt][r] = sigmoidf_fast(gi[rt][r] + gh[rt][r] + bv);
    } else if (gidx == 1) {
      const float bv = bhz[col];
      #pragma unroll
      for (int rt = 0; rt < 2; rt++)
        #pragma unroll
        for (int r = 0; r < 4; r++)
          ZV[rt][r] = sigmoidf_fast(gi[rt][r] + gh[rt][r] + bv);
    } else {
      const float bv = bhn[col];
      #pragma unroll
      for (int rt = 0; rt < 2; rt++)
        #pragma unroll
        for (int r = 0; r < 4; r++) {
          const int row = rt*16 + quad*4 + r;
          float bel = (float)belf[row][col];       // from LDS (f16)
          float pre = gi[rt][r] + RV[rt][r] * (gh[rt][r] + bv);
          float nv = tanhf_fast(pre);
          float nb = (1.f - ZV[rt][r]) * nv + ZV[rt][r] * bel;
          xf[row][col] = (_Float16)nb;             // stash only; stores below
        }
    }
  }
  __syncthreads();

  // Epilogue: stage Wout (f32, 768 vals) into gruf's space; coalesced nb store
  float* woutL = (float*)&gruf[0][0];
  if (t < 192) ((float4*)woutL)[t] = ((const float4*)Wout)[t];
  #pragma unroll
  for (int i = 0; i < 2; i++) {
    const int lin = i*512 + t;
    const int row = lin >> 5, c4 = (lin & 31) * 4;
    float4 o;
    o.x = (float)xf[row][c4+0]; o.y = (float)xf[row][c4+1];
    o.z = (float)xf[row][c4+2]; o.w = (float)xf[row][c4+3];
    *(float4*)&out[(size_t)NACT*A_N + (size_t)(r0+row)*HID + c4] = o;
  }
  __syncthreads();

  // logits
  if (t < 32*NACT) {
    const int row = t / NACT, c = t % NACT;
    float a = bout[c];
    #pragma unroll 8
    for (int k = 0; k < HID; k++)
      a += (float)xf[row][k] * woutL[k*NACT + c];
    out[(size_t)(r0+row)*NACT + c] = a;
  }
}

// ---------------------------------------------------------------------------
extern "C" void kernel_launch(void* const* d_in, const int* in_sizes, int n_in,
                              void* d_out, int out_size, void* d_ws, size_t ws_size,
                              hipStream_t stream) {
  const float* obs     = (const float*)d_in[0];
  const float* beliefs = (const float*)d_in[1];
  const float* W1      = (const float*)d_in[2];
  const float* b1      = (const float*)d_in[3];
  const float* W2      = (const float*)d_in[4];
  const float* b2      = (const float*)d_in[5];
  const float* Wb      = (const float*)d_in[6];
  const float* bb      = (const float*)d_in[7];
  const float* Wg      = (const float*)d_in[8];
  const float* bg      = (const float*)d_in[9];
  const float* Wir     = (const float*)d_in[10];
  const float* Wiz     = (const float*)d_in[11];
  const float* Win     = (const float*)d_in[12];
  const float* Whr     = (const float*)d_in[13];
  const float* bhr     = (const float*)d_in[14];
  const float* Whz     = (const float*)d_in[15];
  const float* bhz     = (const float*)d_in[16];
  const float* Whn     = (const float*)d_in[17];
  const float* bhn     = (const float*)d_in[18];
  const float* Wout    = (const float*)d_in[19];
  const float* bout    = (const float*)d_in[20];
  float* out = (float*)d_out;

  // ws layout (bytes): h2f f16 1MB | bp 1MB | bpT 1MB | ctxp bf16 16MB |
  // sums f32 512KB | WT f16 224KB | W1T 68KB | W2T 8KB
  char* ws = (char*)d_ws;
  _Float16* h2f  = (_Float16*)(ws);
  u16*      bp   = (u16*)(ws + 1048576);
  u16*      bpT  = (u16*)(ws + 2097152);
  u16*      ctxp = (u16*)(ws + 3145728);
  float*    sums = (float*)(ws + 19922944);
  _Float16* WT   = (_Float16*)(ws + 20447232);
  _Float16* W1T  = (_Float16*)(ws + 20676608);
  _Float16* W2T  = (_Float16*)(ws + 20746240);

  hipLaunchKernelGGL(kPrep2, dim3(166), dim3(256), 0, stream,
                     Wg, Wir, Wiz, Win, Whr, Whz, Whn, W1, W2, Wb, beliefs, bb,
                     WT, W1T, W2T, bp, bpT);
  hipLaunchKernelGGL(kM, dim3(640), dim3(256), 0, stream,
                     bp, bpT, ctxp, sums, obs, W1T, b1, W2T, b2, h2f);
  hipLaunchKernelGGL(k3_gru, dim3(256), dim3(512), 0, stream,
                     beliefs, h2f, ctxp, sums, WT, bg, bhr, bhz, bhn, Wout, bout, out);
}

// Round 12
// 152.652 us; speedup vs baseline: 1.1459x; 1.1459x over previous
//
#include <hip/hip_runtime.h>

#define A_N 8192
#define OBS_D 520
#define EMB 64
#define HID 128
#define NACT 6
#define SPLIT 16

typedef short bf16x8 __attribute__((ext_vector_type(8)));
typedef _Float16 half8 __attribute__((ext_vector_type(8)));
typedef float f32x4 __attribute__((ext_vector_type(4)));
typedef unsigned short u16;
typedef unsigned int u32;

#define MFMA_BF(a,b,c) __builtin_amdgcn_mfma_f32_16x16x32_bf16(a,b,c,0,0,0)
#define MFMA_FH(a,b,c) __builtin_amdgcn_mfma_f32_16x16x32_f16(a,b,c,0,0,0)

__device__ inline u32 fbits(float f){ union{float f; u32 u;}v; v.f=f; return v.u; }
__device__ inline float fval(u32 u){ union{u32 u; float f;}v; v.u=u; return v.f; }
__device__ inline u16 f2bf(float f){ u32 u=fbits(f); u += 0x7fffu + ((u>>16)&1u); return (u16)(u>>16); }
// pack trunc-bf16(pe) low, trunc-bf16(po) high
__device__ inline u32 pk_bf(float pe, float po){
  return __builtin_amdgcn_perm(fbits(po), fbits(pe), 0x07060302u);
}
__device__ inline float sigmoidf_fast(float x){
  x = fminf(fmaxf(x, -30.f), 30.f);
  return 1.f / (1.f + __expf(-x));
}
__device__ inline float tanhf_fast(float x){
  x = fminf(fmaxf(x, -15.f), 15.f);
  float e = __expf(-2.f*x);
  return (1.f - e) / (1.f + e);
}

// exp2 constant: (1/sqrt(64)) * log2(e)
#define EXP2C 0.18033688011112042f

// ---------------------------------------------------------------------------
// kPrep2: fused weight-prep + belief projection. 166 blocks x 256. (R8-proven)
// ---------------------------------------------------------------------------
__global__ __launch_bounds__(256) void kPrep2(
    const float* __restrict__ Wg, const float* __restrict__ Wir,
    const float* __restrict__ Wiz, const float* __restrict__ Win,
    const float* __restrict__ Whr, const float* __restrict__ Whz,
    const float* __restrict__ Whn, const float* __restrict__ W1,
    const float* __restrict__ W2, const float* __restrict__ Wb,
    const float* __restrict__ beliefs, const float* __restrict__ bb,
    _Float16* __restrict__ WT, _Float16* __restrict__ W1T,
    _Float16* __restrict__ W2T, u16* __restrict__ bp, u16* __restrict__ bpT)
{
  __shared__ float tile[64][65];
  __shared__ u16 WbL[64][136];
  const int t = threadIdx.x, b = blockIdx.x;

  if (b < 38) {
    const float* src; int k0, c0, srcStride, kValid;
    if (b < 28) {
      const int mi = b >> 2, tl = b & 3;
      src = mi==0?Wg: mi==1?Wir: mi==2?Wiz: mi==3?Win: mi==4?Whr: mi==5?Whz: Whn;
      k0 = (tl >> 1) * 64; c0 = (tl & 1) * 64; srcStride = 128; kValid = 128;
    } else if (b < 37) {
      src = W1; k0 = (b - 28) * 64; c0 = 0; srcStride = 64; kValid = OBS_D;
    } else {
      src = W2; k0 = 0; c0 = 0; srcStride = 64; kValid = 64;
    }
    #pragma unroll
    for (int i = 0; i < 16; i++) {
      const int idx = i * 256 + t;
      const int rr = idx >> 6, cc = idx & 63;   // rr = k-local, cc = c-local
      tile[rr][cc] = (k0 + rr < kValid) ? src[(size_t)(k0 + rr) * srcStride + c0 + cc] : 0.f;
    }
    __syncthreads();
    if (b < 28) {
      const int mi = b >> 2;
      _Float16* dst = WT + (size_t)mi * 16384;
      #pragma unroll
      for (int i = 0; i < 16; i++) {
        const int idx = i * 256 + t;
        const int rr = idx >> 6, cc = idx & 63;  // rr = c-local, cc = k-local
        dst[(size_t)(c0 + rr) * 128 + k0 + cc] = (_Float16)tile[cc][rr];
      }
    } else if (b < 37) {
      #pragma unroll
      for (int i = 0; i < 16; i++) {
        const int idx = i * 256 + t;
        const int rr = idx >> 6, cc = idx & 63;
        if (k0 + cc < 544)
          W1T[(size_t)rr * 544 + k0 + cc] = (_Float16)tile[cc][rr];
      }
    } else {
      #pragma unroll
      for (int i = 0; i < 16; i++) {
        const int idx = i * 256 + t;
        const int rr = idx >> 6, cc = idx & 63;
        W2T[(size_t)rr * 64 + cc] = (_Float16)tile[cc][rr];
      }
    }
  } else {
    // ---------------- belief projection (self-contained) ----------------
    const int lane = t & 63, wid = t >> 6;
    const int m = lane & 15, quad = lane >> 4;
    const int r0 = (b - 38) * 64 + wid * 16;

    // Wb (128x64 f32) -> WbL[c][k] bf16, coalesced float4 reads
    #pragma unroll
    for (int i = 0; i < 8; i++) {
      const int i4 = i * 256 + t;               // 2048 float4s
      float4 w4 = ((const float4*)Wb)[i4];
      const int k = i4 >> 4, c = (i4 & 15) * 4;
      WbL[c+0][k] = f2bf(w4.x); WbL[c+1][k] = f2bf(w4.y);
      WbL[c+2][k] = f2bf(w4.z); WbL[c+3][k] = f2bf(w4.w);
    }
    __syncthreads();

    f32x4 acc[4];
    #pragma unroll
    for (int ct = 0; ct < 4; ct++) acc[ct] = (f32x4){0.f,0.f,0.f,0.f};
    #pragma unroll
    for (int s = 0; s < 4; s++) {
      const int k0 = s*32;
      const float* ap = beliefs + (size_t)(r0+m)*HID + k0 + quad*8;
      float4 a0 = *(const float4*)ap;
      float4 a1 = *(const float4*)(ap + 4);
      union { u16 e[8]; bf16x8 v; } av;
      av.e[0]=f2bf(a0.x); av.e[1]=f2bf(a0.y); av.e[2]=f2bf(a0.z); av.e[3]=f2bf(a0.w);
      av.e[4]=f2bf(a1.x); av.e[5]=f2bf(a1.y); av.e[6]=f2bf(a1.z); av.e[7]=f2bf(a1.w);
      #pragma unroll
      for (int ct = 0; ct < 4; ct++) {
        bf16x8 bw = *(const bf16x8*)&WbL[ct*16+m][k0 + quad*8];
        acc[ct] = MFMA_BF(av.v, bw, acc[ct]);
      }
    }
    #pragma unroll
    for (int ct = 0; ct < 4; ct++) {
      const int col = ct*16 + m;
      const float bbv = bb[col];
      u16 e[4];
      #pragma unroll
      for (int r = 0; r < 4; r++) e[r] = f2bf(acc[ct][r] + bbv);
      #pragma unroll
      for (int r = 0; r < 4; r++)
        bp[(size_t)(r0 + quad*4 + r)*EMB + col] = e[r];
      uint2 pkv;
      pkv.x = (u32)e[0] | ((u32)e[1] << 16);
      pkv.y = (u32)e[2] | ((u32)e[3] << 16);
      *(uint2*)(bpT + (size_t)col*A_N + r0 + quad*4) = pkv;
    }
  }
}

// ---------------------------------------------------------------------------
// kM: blocks 0..127 = obs-MLP; blocks 128..639 = flash attention.
// R12 = exact R10 body (the R11 register-hoist regressed: it serialized the
// LDS-read burst ahead of the MFMAs and doubled bank-conflict cycles; R10's
// compiler-interleaved LDS reads overlap MFMA issue and are effectively free).
// Block-cooperative double-buffered K/V^T staging, one barrier per tile.
// ---------------------------------------------------------------------------
__global__ __launch_bounds__(256) void kM(
    const u16* __restrict__ bp, const u16* __restrict__ bpT,
    u16* __restrict__ ctxp, float* __restrict__ sums,
    const float* __restrict__ obs, const _Float16* __restrict__ W1T,
    const float* __restrict__ b1, const _Float16* __restrict__ W2T,
    const float* __restrict__ b2, _Float16* __restrict__ h2f)
{
  __shared__ __align__(16) u16 KT[2][64*72];    // K tile,  18432 B
  __shared__ __align__(16) u16 VTl[2][64*72];   // V^T tile, 18432 B
  __shared__ __align__(16) u16 P2[4][2][16*72]; // per-wave P (2 frags), 18432 B
  const int tid = threadIdx.x;
  const int lane = tid & 63;
  const int wid  = tid >> 6;
  const int m = lane & 15, quad = lane >> 4;

  if (blockIdx.x >= 128) {
    // ------------------------- attention -------------------------
    const int ab = blockIdx.x - 128;          // 0..511
    const int split = ab >> 5;                // whole block shares one split
    const int qb = ab & 31;
    const int q0w = qb * 256 + wid * 64;      // wave's 64 q-rows
    const int kbeg = split * (A_N / SPLIT);

    bf16x8 qa[4][2];
    #pragma unroll
    for (int f = 0; f < 4; f++) {
      const u16* qr = bp + (size_t)(q0w + f*16 + m)*EMB + quad*8;
      qa[f][0] = *(const bf16x8*)(qr);
      qa[f][1] = *(const bf16x8*)(qr + 32);
    }
    f32x4 oacc[4][4];   // [f][dtt]
    #pragma unroll
    for (int f = 0; f < 4; f++)
      #pragma unroll
      for (int d = 0; d < 4; d++) oacc[f][d] = (f32x4){0.f,0.f,0.f,0.f};
    float rowsum[4] = {0.f, 0.f, 0.f, 0.f};

    uint4 kreg[2], vreg[2];
    const int srow0 = tid >> 3, seg = tid & 7;        // iter0 row, 16B segment
    const int srow1 = (256 + tid) >> 3;               // iter1 row

    // preload tile 0 -> buffer 0
    kreg[0] = *(const uint4*)(bp + (size_t)(kbeg + srow0)*EMB + seg*8);
    kreg[1] = *(const uint4*)(bp + (size_t)(kbeg + srow1)*EMB + seg*8);
    vreg[0] = *(const uint4*)(bpT + (size_t)srow0*A_N + kbeg + seg*8);
    vreg[1] = *(const uint4*)(bpT + (size_t)srow1*A_N + kbeg + seg*8);
    *(uint4*)&KT[0][srow0*72 + seg*8] = kreg[0];
    *(uint4*)&KT[0][srow1*72 + seg*8] = kreg[1];
    *(uint4*)&VTl[0][srow0*72 + seg*8] = vreg[0];
    *(uint4*)&VTl[0][srow1*72 + seg*8] = vreg[1];
    __syncthreads();

    for (int tt = 0; tt < 8; tt++) {
      const int k0 = kbeg + tt*64;
      const int cur = tt & 1;
      if (tt < 7) {   // issue next tile's loads now; consumed after compute
        const int kn = k0 + 64;
        kreg[0] = *(const uint4*)(bp + (size_t)(kn + srow0)*EMB + seg*8);
        kreg[1] = *(const uint4*)(bp + (size_t)(kn + srow1)*EMB + seg*8);
        vreg[0] = *(const uint4*)(bpT + (size_t)srow0*A_N + kn + seg*8);
        vreg[1] = *(const uint4*)(bpT + (size_t)srow1*A_N + kn + seg*8);
      }
      // compute in 2 halves of Q-frags (halves share the wave's P buffer pair)
      #pragma unroll
      for (int h = 0; h < 2; h++) {
        #pragma unroll
        for (int jt = 0; jt < 4; jt++) {
          const bf16x8 kb0 = *(const bf16x8*)&KT[cur][(jt*16+m)*72 + quad*8];
          const bf16x8 kb1 = *(const bf16x8*)&KT[cur][(jt*16+m)*72 + 32 + quad*8];
          #pragma unroll
          for (int fi = 0; fi < 2; fi++) {
            const int f = h*2 + fi;
            f32x4 s = (f32x4){0.f,0.f,0.f,0.f};
            s = MFMA_BF(kb0, qa[f][0], s);
            s = MFMA_BF(kb1, qa[f][1], s);
            float p0 = __builtin_amdgcn_exp2f(s[0]*EXP2C);
            float p1 = __builtin_amdgcn_exp2f(s[1]*EXP2C);
            float p2 = __builtin_amdgcn_exp2f(s[2]*EXP2C);
            float p3 = __builtin_amdgcn_exp2f(s[3]*EXP2C);
            if ((k0 + jt*16) == (q0w + f*16)) {   // wave-uniform diag tile
              const int jl = quad*4;
              if (jl + 0 == m) p0 = 0.f;
              if (jl + 1 == m) p1 = 0.f;
              if (jl + 2 == m) p2 = 0.f;
              if (jl + 3 == m) p3 = 0.f;
            }
            rowsum[f] += (p0 + p1) + (p2 + p3);
            uint2 pkv; pkv.x = pk_bf(p0, p1); pkv.y = pk_bf(p2, p3);
            *(uint2*)&P2[wid][fi][m*72 + jt*16 + quad*4] = pkv;
          }
        }
        // wave-local ds_write -> ds_read ordering (no block barrier)
        asm volatile("s_waitcnt lgkmcnt(0)" ::: "memory");
        #pragma unroll
        for (int fi = 0; fi < 2; fi++) {
          const int f = h*2 + fi;
          const bf16x8 pa0 = *(const bf16x8*)&P2[wid][fi][m*72 + quad*8];
          const bf16x8 pa1 = *(const bf16x8*)&P2[wid][fi][m*72 + 32 + quad*8];
          #pragma unroll
          for (int dtt = 0; dtt < 4; dtt++) {
            const bf16x8 vb0 = *(const bf16x8*)&VTl[cur][(dtt*16+m)*72 + quad*8];
            const bf16x8 vb1 = *(const bf16x8*)&VTl[cur][(dtt*16+m)*72 + 32 + quad*8];
            oacc[f][dtt] = MFMA_BF(pa0, vb0, oacc[f][dtt]);
            oacc[f][dtt] = MFMA_BF(pa1, vb1, oacc[f][dtt]);
          }
        }
      }
      if (tt < 7) {   // write next tile into idle buffer; single barrier
        const int nxt = cur ^ 1;
        *(uint4*)&KT[nxt][srow0*72 + seg*8] = kreg[0];
        *(uint4*)&KT[nxt][srow1*72 + seg*8] = kreg[1];
        *(uint4*)&VTl[nxt][srow0*72 + seg*8] = vreg[0];
        *(uint4*)&VTl[nxt][srow1*72 + seg*8] = vreg[1];
        __syncthreads();
      }
    }

    // rowsum for query q=m (per frag): reduce across the 4 quads
    #pragma unroll
    for (int f = 0; f < 4; f++) {
      float v = rowsum[f];
      v += __shfl_xor(v, 16, 64);
      v += __shfl_xor(v, 32, 64);
      if (lane < 16)
        sums[(size_t)split*A_N + q0w + f*16 + lane] = v;
    }
    // oacc[f][dtt][r] = ctx[q = q0w+f*16+quad*4+r][d = dtt*16+m]
    #pragma unroll
    for (int f = 0; f < 4; f++) {
      const size_t base = ((size_t)split*A_N + q0w + f*16) * EMB;
      #pragma unroll
      for (int dtt = 0; dtt < 4; dtt++)
        #pragma unroll
        for (int r = 0; r < 4; r++)
          ctxp[base + (size_t)(quad*4+r)*EMB + dtt*16 + m] = f2bf(oacc[f][dtt][r]);
    }
  } else {
    // ------------------------- obs-MLP -------------------------
    const int r0 = blockIdx.x * 64 + wid * 16;
    f32x4 oa[4];
    #pragma unroll
    for (int ct = 0; ct < 4; ct++) oa[ct] = (f32x4){0.f,0.f,0.f,0.f};

    for (int s = 0; s < 17; s++) {
      const int k0 = s * 32;
      union { _Float16 e[8]; half8 v; } af;
      if (s < 16) {
        const float* ap = obs + (size_t)(r0+m)*OBS_D + k0 + quad*8;
        float4 a0 = *(const float4*)ap;
        float4 a1 = *(const float4*)(ap + 4);
        af.e[0]=(_Float16)a0.x; af.e[1]=(_Float16)a0.y; af.e[2]=(_Float16)a0.z; af.e[3]=(_Float16)a0.w;
        af.e[4]=(_Float16)a1.x; af.e[5]=(_Float16)a1.y; af.e[6]=(_Float16)a1.z; af.e[7]=(_Float16)a1.w;
      } else {
        #pragma unroll
        for (int j = 0; j < 8; j++) af.e[j] = (_Float16)0.f;
        if (quad == 0) {
          const float* ap = obs + (size_t)(r0+m)*OBS_D + 512;
          float4 a0 = *(const float4*)ap;
          float4 a1 = *(const float4*)(ap + 4);
          af.e[0]=(_Float16)a0.x; af.e[1]=(_Float16)a0.y; af.e[2]=(_Float16)a0.z; af.e[3]=(_Float16)a0.w;
          af.e[4]=(_Float16)a1.x; af.e[5]=(_Float16)a1.y; af.e[6]=(_Float16)a1.z; af.e[7]=(_Float16)a1.w;
        }
      }
      #pragma unroll
      for (int ct = 0; ct < 4; ct++) {
        half8 bw = *(const half8*)(W1T + (size_t)(ct*16+m)*544 + k0 + quad*8);
        oa[ct] = MFMA_FH(af.v, bw, oa[ct]);
      }
    }
    _Float16* H1 = (_Float16*)&P2[wid][0][0];
    #pragma unroll
    for (int ct = 0; ct < 4; ct++) {
      const float b1v = b1[ct*16 + m];
      #pragma unroll
      for (int r = 0; r < 4; r++) {
        float v = fmaxf(oa[ct][r] + b1v, 0.f);
        H1[(quad*4+r)*72 + ct*16 + m] = (_Float16)v;
      }
    }
    __syncthreads();   // MLP blocks uniform; orders H1 write -> read
    f32x4 ob[4];
    #pragma unroll
    for (int ct = 0; ct < 4; ct++) ob[ct] = (f32x4){0.f,0.f,0.f,0.f};
    #pragma unroll
    for (int s2 = 0; s2 < 2; s2++) {
      half8 ah = *(const half8*)(H1 + m*72 + s2*32 + quad*8);
      #pragma unroll
      for (int ct = 0; ct < 4; ct++) {
        half8 bw = *(const half8*)(W2T + (size_t)(ct*16+m)*64 + s2*32 + quad*8);
        ob[ct] = MFMA_FH(ah, bw, ob[ct]);
      }
    }
    #pragma unroll
    for (int ct = 0; ct < 4; ct++) {
      const float b2v = b2[ct*16 + m];
      #pragma unroll
      for (int r = 0; r < 4; r++) {
        float v = fmaxf(ob[ct][r] + b2v, 0.f);
        h2f[(size_t)(r0 + quad*4 + r)*EMB + ct*16 + m] = (_Float16)v;
      }
    }
  }
}

// ---------------------------------------------------------------------------
// k3: split-reduce + GRU + logits. 32 rows/block, 256 blocks, 8 waves (512t).
// (R11 structure, kept: 2x waves/CU at identical weight VMEM; neutral-to-
// positive vs 256t and lower per-wave VGPR.)
// ---------------------------------------------------------------------------
__global__ __launch_bounds__(512) void k3_gru(
    const float* __restrict__ beliefs, const _Float16* __restrict__ h2f,
    const u16* __restrict__ ctxp, const float* __restrict__ sums,
    const _Float16* __restrict__ WT,
    const float* __restrict__ bg, const float* __restrict__ bhr,
    const float* __restrict__ bhz, const float* __restrict__ bhn,
    const float* __restrict__ Wout, const float* __restrict__ bout,
    float* __restrict__ out)
{
  __shared__ __align__(16) _Float16 xf[32][136];   // x = [h2|ctx]; then new_beliefs
  __shared__ __align__(16) _Float16 belf[32][136];
  __shared__ __align__(16) _Float16 gruf[32][136]; // gru_in; tail: Wout f32 stage
  const int t = threadIdx.x;
  const int lane = t & 63, wid = t >> 6;           // wid 0..7 = col-tile
  const int m = lane & 15, quad = lane >> 4;
  const int r0 = blockIdx.x * 32;

  // Phase 0a: stage beliefs (f16) into LDS — 512 threads, one slot each
  {
    const int row = t >> 4, seg = t & 15;
    const float* bpR = beliefs + (size_t)(r0+row)*HID + seg*8;
    float4 a0 = *(const float4*)bpR;
    float4 a1 = *(const float4*)(bpR + 4);
    union { _Float16 e[8]; half8 v; } hb;
    hb.e[0]=(_Float16)a0.x; hb.e[1]=(_Float16)a0.y; hb.e[2]=(_Float16)a0.z; hb.e[3]=(_Float16)a0.w;
    hb.e[4]=(_Float16)a1.x; hb.e[5]=(_Float16)a1.y; hb.e[6]=(_Float16)a1.z; hb.e[7]=(_Float16)a1.w;
    *(half8*)&belf[row][seg*8] = hb.v;
  }
  // Phase 0b: h2 into xf; ctx split-reduce in registers (first 256 threads)
  if (t < 256) {
    const int crow = t >> 3, cg = t & 7;
    half8 hv = *(const half8*)(h2f + (size_t)(r0+crow)*EMB + cg*8);
    *(half8*)&xf[crow][cg*8] = hv;
    float ca[8];
    #pragma unroll
    for (int d = 0; d < 8; d++) ca[d] = 0.f;
    #pragma unroll
    for (int sp = 0; sp < SPLIT; sp++) {
      uint4 u = *(const uint4*)(ctxp + ((size_t)sp*A_N + r0 + crow)*EMB + cg*8);
      ca[0] += fval(u.x << 16); ca[1] += fval(u.x & 0xffff0000u);
      ca[2] += fval(u.y << 16); ca[3] += fval(u.y & 0xffff0000u);
      ca[4] += fval(u.z << 16); ca[5] += fval(u.z & 0xffff0000u);
      ca[6] += fval(u.w << 16); ca[7] += fval(u.w & 0xffff0000u);
    }
    float ss = 0.f;
    #pragma unroll
    for (int sp = 0; sp < SPLIT; sp++) ss += sums[(size_t)sp*A_N + r0 + crow];
    const float iv = 1.f / ss;
    union { _Float16 e[8]; half8 v; } hc;
    #pragma unroll
    for (int d = 0; d < 8; d++) hc.e[d] = (_Float16)(ca[d] * iv);
    *(half8*)&xf[crow][64 + cg*8] = hc.v;
  }
  __syncthreads();

  // Phase 1: gru_in = x @ Wg + bg  (wave owns col-tile wid x 2 row-tiles)
  f32x4 g[2];   // [rt]
  g[0] = (f32x4){0.f,0.f,0.f,0.f}; g[1] = (f32x4){0.f,0.f,0.f,0.f};
  #pragma unroll
  for (int s = 0; s < 4; s++) {
    half8 bw = *(const half8*)(WT + (size_t)(wid*16+m)*128 + s*32 + quad*8);
    #pragma unroll
    for (int rt = 0; rt < 2; rt++) {
      half8 ax = *(const half8*)&xf[rt*16 + m][s*32 + quad*8];
      g[rt] = MFMA_FH(ax, bw, g[rt]);
    }
  }
  {
    const int col = wid*16 + m;
    const float bgv = bg[col];
    #pragma unroll
    for (int rt = 0; rt < 2; rt++)
      #pragma unroll
      for (int r = 0; r < 4; r++)
        gruf[rt*16 + quad*4 + r][col] = (_Float16)(g[rt][r] + bgv);
  }
  __syncthreads();

  // Phase 2: gates
  f32x4 RV[2], ZV[2];
  #pragma unroll
  for (int gidx = 0; gidx < 3; gidx++) {
    const _Float16* WiTg = WT + (size_t)(1+gidx)*16384;
    const _Float16* WhTg = WT + (size_t)(4+gidx)*16384;
    f32x4 gi[2], gh[2];
    gi[0]=(f32x4){0.f,0.f,0.f,0.f}; gi[1]=(f32x4){0.f,0.f,0.f,0.f};
    gh[0]=(f32x4){0.f,0.f,0.f,0.f}; gh[1]=(f32x4){0.f,0.f,0.f,0.f};
    #pragma unroll
    for (int s = 0; s < 4; s++) {
      half8 bi = *(const half8*)(WiTg + (size_t)(wid*16+m)*128 + s*32 + quad*8);
      half8 bh = *(const half8*)(WhTg + (size_t)(wid*16+m)*128 + s*32 + quad*8);
      #pragma unroll
      for (int rt = 0; rt < 2; rt++) {
        half8 ag = *(const half8*)&gruf[rt*16 + m][s*32 + quad*8];
        half8 ab = *(const half8*)&belf[rt*16 + m][s*32 + quad*8];
        gi[rt] = MFMA_FH(ag, bi, gi[rt]);
        gh[rt] = MFMA_FH(ab, bh, gh[rt]);
      }
    }
    const int col = wid*16 + m;
    if (gidx == 0) {
      const float bv = bhr[col];
      #pragma unroll
      for (int rt = 0; rt < 2; rt++)
        #pragma unroll
        for (int r = 0; r < 4; r++)
          RV[rt][r] = sigmoidf_fast(gi[rt][r] + gh[rt][r] + bv);
    } else if (gidx == 1) {
      const float bv = bhz[col];
      #pragma unroll
      for (int rt = 0; rt < 2; rt++)
        #pragma unroll
        for (int r = 0; r < 4; r++)
          ZV[rt][r] = sigmoidf_fast(gi[rt][r] + gh[rt][r] + bv);
    } else {
      const float bv = bhn[col];
      #pragma unroll
      for (int rt = 0; rt < 2; rt++)
        #pragma unroll
        for (int r = 0; r < 4; r++) {
          const int row = rt*16 + quad*4 + r;
          float bel = (float)belf[row][col];       // from LDS (f16)
          float pre = gi[rt][r] + RV[rt][r] * (gh[rt][r] + bv);
          float nv = tanhf_fast(pre);
          float nb = (1.f - ZV[rt][r]) * nv + ZV[rt][r] * bel;
          xf[row][col] = (_Float16)nb;             // stash only; stores below
        }
    }
  }
  __syncthreads();

  // Epilogue: stage Wout (f32, 768 vals) into gruf's space; coalesced nb store
  float* woutL = (float*)&gruf[0][0];
  if (t < 192) ((float4*)woutL)[t] = ((const float4*)Wout)[t];
  #pragma unroll
  for (int i = 0; i < 2; i++) {
    const int lin = i*512 + t;
    const int row = lin >> 5, c4 = (lin & 31) * 4;
    float4 o;
    o.x = (float)xf[row][c4+0]; o.y = (float)xf[row][c4+1];
    o.z = (float)xf[row][c4+2]; o.w = (float)xf[row][c4+3];
    *(float4*)&out[(size_t)NACT*A_N + (size_t)(r0+row)*HID + c4] = o;
  }
  __syncthreads();

  // logits
  if (t < 32*NACT) {
    const int row = t / NACT, c = t % NACT;
    float a = bout[c];
    #pragma unroll 8
    for (int k = 0; k < HID; k++)
      a += (float)xf[row][k] * woutL[k*NACT + c];
    out[(size_t)(r0+row)*NACT + c] = a;
  }
}

// ---------------------------------------------------------------------------
extern "C" void kernel_launch(void* const* d_in, const int* in_sizes, int n_in,
                              void* d_out, int out_size, void* d_ws, size_t ws_size,
                              hipStream_t stream) {
  const float* obs     = (const float*)d_in[0];
  const float* beliefs = (const float*)d_in[1];
  const float* W1      = (const float*)d_in[2];
  const float* b1      = (const float*)d_in[3];
  const float* W2      = (const float*)d_in[4];
  const float* b2      = (const float*)d_in[5];
  const float* Wb      = (const float*)d_in[6];
  const float* bb      = (const float*)d_in[7];
  const float* Wg      = (const float*)d_in[8];
  const float* bg      = (const float*)d_in[9];
  const float* Wir     = (const float*)d_in[10];
  const float* Wiz     = (const float*)d_in[11];
  const float* Win     = (const float*)d_in[12];
  const float* Whr     = (const float*)d_in[13];
  const float* bhr     = (const float*)d_in[14];
  const float* Whz     = (const float*)d_in[15];
  const float* bhz     = (const float*)d_in[16];
  const float* Whn     = (const float*)d_in[17];
  const float* bhn     = (const float*)d_in[18];
  const float* Wout    = (const float*)d_in[19];
  const float* bout    = (const float*)d_in[20];
  float* out = (float*)d_out;

  // ws layout (bytes): h2f f16 1MB | bp 1MB | bpT 1MB | ctxp bf16 16MB |
  // sums f32 512KB | WT f16 224KB | W1T 68KB | W2T 8KB
  char* ws = (char*)d_ws;
  _Float16* h2f  = (_Float16*)(ws);
  u16*      bp   = (u16*)(ws + 1048576);
  u16*      bpT  = (u16*)(ws + 2097152);
  u16*      ctxp = (u16*)(ws + 3145728);
  float*    sums = (float*)(ws + 19922944);
  _Float16* WT   = (_Float16*)(ws + 20447232);
  _Float16* W1T  = (_Float16*)(ws + 20676608);
  _Float16* W2T  = (_Float16*)(ws + 20746240);

  hipLaunchKernelGGL(kPrep2, dim3(166), dim3(256), 0, stream,
                     Wg, Wir, Wiz, Win, Whr, Whz, Whn, W1, W2, Wb, beliefs, bb,
                     WT, W1T, W2T, bp, bpT);
  hipLaunchKernelGGL(kM, dim3(640), dim3(256), 0, stream,
                     bp, bpT, ctxp, sums, obs, W1T, b1, W2T, b2, h2f);
  hipLaunchKernelGGL(k3_gru, dim3(256), dim3(512), 0, stream,
                     beliefs, h2f, ctxp, sums, WT, bg, bhr, bhz, bhn, Wout, bout, out);
}